// Round 3
// baseline (1220.202 us; speedup 1.0000x reference)
//
#include <hip/hip_runtime.h>
#include <hip/hip_cooperative_groups.h>
namespace cg = cooperative_groups;

#define Bn 4
#define Nn 4096000
#define Kn 409664
#define R0c 3686399u   // rank of v_lo; mask == key > key_lo exactly (adjacent order stats)
#define NWC 4000       // 1024-element wave-chunks per sample
#define CAP 4096       // candidate buffer capacity per sample (expect ~250)

// ws offsets (u32 units)
#define H1_OFF 0                     // Bn*2048
#define H2_OFF (H1_OFF + Bn*2048)    // Bn*2048
#define H3_OFF (H2_OFF + Bn*2048)    // Bn*1024
#define ST_OFF (H3_OFF + Bn*1024)    // Bn*2  {prefix/key, rem}
#define CNT_OFF (ST_OFF + Bn*2)      // Bn    per-sample totals
#define CN_OFF (CNT_OFF + Bn)        // Bn    candidate counters
#define BC_OFF (CN_OFF + Bn)         // Bn*NWC wave-chunk counts -> exclusive prefix
#define CAND_OFF (BC_OFF + Bn*NWC)   // Bn*CAP packed (wc<<10)|low10

#define OUT_SP  ((size_t)Bn * Kn * 5)
#define OUT_VAL ((size_t)Bn * Kn * 9)

__device__ __forceinline__ unsigned fkey(float x) {
    unsigned u = __float_as_uint(x);
    return u ^ ((unsigned)((int)u >> 31) | 0x80000000u);
}

// block-level rank walk over a histogram slice (only blocks < Bn call this)
__device__ __forceinline__ void pick_step(unsigned* smem, const unsigned* __restrict__ hist,
                                          int per, unsigned r, unsigned pref, int shift,
                                          unsigned* st) {
    int tid = threadIdx.x;
    unsigned loc[8], lsum = 0;
    for (int j = 0; j < per; ++j) { loc[j] = hist[tid * per + j]; lsum += loc[j]; }
    smem[tid] = lsum; __syncthreads();
    for (int off = 1; off < 256; off <<= 1) {
        unsigned v = (tid >= off) ? smem[tid - off] : 0u; __syncthreads();
        smem[tid] += v; __syncthreads();
    }
    unsigned base = tid ? smem[tid - 1] : 0u;
    if (r >= base && r < base + lsum) {
        unsigned cacc = base;
        for (int j = 0; j < per; ++j) {
            if (r < cacc + loc[j]) {
                st[0] = (pref << shift) | (unsigned)(tid * per + j);
                st[1] = r - cacc;
                break;
            }
            cacc += loc[j];
        }
    }
    __syncthreads();
}

__global__ __launch_bounds__(256, 4) void mega_k(const float* __restrict__ cube,
                                                 const float* __restrict__ dop,
                                                 float* __restrict__ out,
                                                 unsigned* __restrict__ ws) {
    cg::grid_group grid = cg::this_grid();
    __shared__ unsigned smem[8192];   // 32 KB
    const int tid = threadIdx.x, blk = blockIdx.x;
    const int lane = tid & 63, wid = tid >> 6;
    const int b = blk / 250, c250 = blk % 250;
    const float* cb = cube + (size_t)b * Nn;

    // ---- P0: zero histograms + candidate counters ----
    for (int j = blk * 256 + tid; j < ST_OFF; j += 1000 * 256) ws[j] = 0;
    if (blk == 0 && tid < Bn) ws[CN_OFF + tid] = 0;
    grid.sync();

    // ---- P1: hist over top 11 bits (4 per-wave LDS copies) ----
    {
        for (int j = tid; j < 8192; j += 256) smem[j] = 0;
        __syncthreads();
        unsigned* h = smem + (wid << 11);
        const float4* p = (const float4*)(cb + (size_t)c250 * 16384);
        for (int it = 0; it < 16; ++it) {
            float4 v = p[it * 256 + tid];
            atomicAdd(&h[fkey(v.x) >> 21], 1u);
            atomicAdd(&h[fkey(v.y) >> 21], 1u);
            atomicAdd(&h[fkey(v.z) >> 21], 1u);
            atomicAdd(&h[fkey(v.w) >> 21], 1u);
        }
        __syncthreads();
        unsigned* g = ws + H1_OFF + b * 2048;
        for (int j = tid; j < 2048; j += 256) {
            unsigned s = smem[j] + smem[2048 + j] + smem[4096 + j] + smem[6144 + j];
            if (s) atomicAdd(&g[j], s);
        }
    }
    grid.sync();

    // ---- P2: pick1 ----
    if (blk < Bn)
        pick_step(smem, ws + H1_OFF + blk * 2048, 8, R0c, 0u, 0, ws + ST_OFF + blk * 2);
    grid.sync();

    // ---- P3: hist over middle 11 bits, gated on 11-bit prefix ----
    {
        unsigned p11 = ws[ST_OFF + b * 2];
        for (int j = tid; j < 2048; j += 256) smem[j] = 0;
        __syncthreads();
        const float4* p = (const float4*)(cb + (size_t)c250 * 16384);
        for (int it = 0; it < 16; ++it) {
            float4 v = p[it * 256 + tid];
            float vv[4] = {v.x, v.y, v.z, v.w};
            for (int q = 0; q < 4; ++q) {
                unsigned k = fkey(vv[q]);
                if ((k >> 21) == p11) atomicAdd(&smem[(k >> 10) & 0x7FFu], 1u);
            }
        }
        __syncthreads();
        unsigned* g = ws + H2_OFF + b * 2048;
        for (int j = tid; j < 2048; j += 256) if (smem[j]) atomicAdd(&g[j], smem[j]);
    }
    grid.sync();

    // ---- P4: pick2 ----
    if (blk < Bn) {
        unsigned pref = ws[ST_OFF + blk * 2], r = ws[ST_OFF + blk * 2 + 1];
        pick_step(smem, ws + H2_OFF + blk * 2048, 8, r, pref, 11, ws + ST_OFF + blk * 2);
    }
    grid.sync();

    // ---- P5: per-wave-chunk A-counts (top22 > p22) + tiny candidate compact + hist3 ----
    {
        unsigned p22 = ws[ST_OFF + b * 2];
        unsigned* H3g = ws + H3_OFF + b * 1024;
        for (int j = 0; j < 4; ++j) {
            int wc = c250 * 16 + wid * 4 + j;
            const float4* p = (const float4*)(cb + (size_t)wc * 1024);
            unsigned acnt = 0;
#define P5_ELEM(val) { unsigned k = fkey(val); acnt += ((k >> 10) > p22) ? 1u : 0u; \
    if ((k >> 10) == p22) { unsigned t = atomicAdd(&ws[CN_OFF + b], 1u); \
        if (t < CAP) ws[CAND_OFF + b * CAP + t] = ((unsigned)wc << 10) | (k & 1023u); \
        atomicAdd(&H3g[k & 1023u], 1u); } }
            for (int it = 0; it < 4; ++it) {
                float4 v = p[it * 64 + lane];
                P5_ELEM(v.x) P5_ELEM(v.y) P5_ELEM(v.z) P5_ELEM(v.w)
            }
#undef P5_ELEM
            for (int off = 32; off > 0; off >>= 1) acnt += __shfl_down(acnt, off, 64);
            if (lane == 0) ws[BC_OFF + b * NWC + wc] = acnt;
        }
    }
    grid.sync();

    // ---- P6: pick3 -> final 32-bit key_lo ----
    if (blk < Bn) {
        unsigned pref = ws[ST_OFF + blk * 2], r = ws[ST_OFF + blk * 2 + 1];
        pick_step(smem, ws + H3_OFF + blk * 1024, 4, r, pref, 10, ws + ST_OFF + blk * 2);
    }
    grid.sync();

    // ---- P7a: candidate fix-up (add low10 > lo10 members to chunk counts) ----
    if (blk < Bn) {
        unsigned lo10 = ws[ST_OFF + blk * 2] & 1023u;
        unsigned n = ws[CN_OFF + blk]; if (n > CAP) n = CAP;
        for (unsigned t = tid; t < n; t += 256) {
            unsigned e = ws[CAND_OFF + blk * CAP + t];
            if ((e & 1023u) > lo10) atomicAdd(&ws[BC_OFF + blk * NWC + (e >> 10)], 1u);
        }
    }
    grid.sync();

    // ---- P7b: exclusive scan of 4000 chunk counts per sample ----
    if (blk < Bn) {
        unsigned* bc = ws + BC_OFF + blk * NWC;
        unsigned loc[16], lsum = 0;
        for (int j = 0; j < 16; ++j) {
            int idx = tid * 16 + j;
            loc[j] = (idx < NWC) ? bc[idx] : 0u;
            lsum += loc[j];
        }
        smem[tid] = lsum; __syncthreads();
        for (int off = 1; off < 256; off <<= 1) {
            unsigned v = (tid >= off) ? smem[tid - off] : 0u; __syncthreads();
            smem[tid] += v; __syncthreads();
        }
        unsigned run = tid ? smem[tid - 1] : 0u;
        for (int j = 0; j < 16; ++j) {
            int idx = tid * 16 + j;
            if (idx < NWC) bc[idx] = run;
            run += loc[j];
        }
        if (tid == 255) ws[CNT_OFF + blk] = smem[255];
        __syncthreads();
    }
    grid.sync();

    // ---- P8: barrier-free ordered scatter (round-1 store pattern) + tail fill ----
    {
        unsigned keylo = ws[ST_OFF + b * 2];
        const float* db = dop + (size_t)b * Nn;
        for (int j = 0; j < 4; ++j) {
            int wc = c250 * 16 + wid * 4 + j;
            unsigned run = ws[BC_OFF + b * NWC + wc];
            int base = wc * 1024;
#pragma unroll 4
            for (int it = 0; it < 16; ++it) {
                int i = base + it * 64 + lane;
                float x = cb[i];
                bool m = fkey(x) > keylo;
                unsigned long long bal = __ballot(m);
                if (m) {
                    unsigned k = run + (unsigned)__popcll(bal & ((1ull << lane) - 1ull));
                    size_t row = (size_t)b * Kn + k;
                    int xi = i % 320;
                    int t2 = i / 320;
                    int yi = t2 % 320;
                    int zi = t2 / 320;
                    float* f = out + row * 5;
                    f[0] = (float)xi / 320.0f * 72.0f;
                    f[1] = (float)yi / 320.0f * 32.0f;
                    f[2] = (float)zi / 40.0f * 8.0f;
                    f[3] = x / 1e13f;
                    f[4] = db[i] - 1.9326f;
                    float* s = out + OUT_SP + row * 4;
                    s[0] = (float)b; s[1] = (float)zi; s[2] = (float)yi; s[3] = (float)xi;
                    out[OUT_VAL + row] = 1.0f;
                }
                run += (unsigned)__popcll(bal);
            }
        }
        // tail fill (outputs are poisoned before every launch)
        for (int g = blk * 256 + tid; g < Bn * Kn; g += 1000 * 256) {
            int bb = g / Kn;
            int k = g - bb * Kn;
            if ((unsigned)k >= ws[CNT_OFF + bb]) {
                size_t row = (size_t)g;
                float* f = out + row * 5;
                f[0] = 0.f; f[1] = 0.f; f[2] = 0.f; f[3] = 0.f; f[4] = 0.f;
                float* s = out + OUT_SP + row * 4;
                s[0] = 0.f; s[1] = 0.f; s[2] = 0.f; s[3] = 0.f;
                out[OUT_VAL + row] = 0.f;
            }
        }
    }
}

extern "C" void kernel_launch(void* const* d_in, const int* in_sizes, int n_in,
                              void* d_out, int out_size, void* d_ws, size_t ws_size,
                              hipStream_t stream) {
    const float* cube = (const float*)d_in[0];
    const float* dop = (const float*)d_in[1];
    float* out = (float*)d_out;
    unsigned* ws = (unsigned*)d_ws;
    void* args[] = {(void*)&cube, (void*)&dop, (void*)&out, (void*)&ws};
    hipLaunchCooperativeKernel((const void*)mega_k, dim3(1000), dim3(256), args, 0, stream);
}

// Round 4
// 284.192 us; speedup vs baseline: 4.2936x; 4.2936x over previous
//
#include <hip/hip_runtime.h>

#define Bn 4
#define Nn 4096000
#define Kn 409664
#define R0c 3686399u   // rank of v_lo; mask == key > key_lo exactly (adjacent order stats)
#define NWC 4000       // 1024-element wave-chunks per sample
#define CAP 4096       // candidate buffer capacity per sample (expect ~250)

// ws offsets (u32 units)
#define H1_OFF 0                     // Bn*2048
#define H2_OFF (H1_OFF + Bn*2048)    // Bn*2048
#define H3_OFF (H2_OFF + Bn*2048)    // Bn*1024
#define ST_OFF (H3_OFF + Bn*1024)    // Bn*2  {prefix/key, rem}
#define CNT_OFF (ST_OFF + Bn*2)      // Bn    per-sample totals
#define CN_OFF (CNT_OFF + Bn)        // Bn    candidate counters
#define BC_OFF (CN_OFF + Bn)         // Bn*NWC wave-chunk counts -> exclusive prefix
#define CAND_OFF (BC_OFF + Bn*NWC)   // Bn*CAP packed (wc<<10)|low10

#define OUT_SP  ((size_t)Bn * Kn * 5)
#define OUT_VAL ((size_t)Bn * Kn * 9)

__device__ __forceinline__ unsigned fkey(float x) {
    unsigned u = __float_as_uint(x);
    return u ^ ((unsigned)((int)u >> 31) | 0x80000000u);
}

// ---------------- hist1: top 11 bits, 4 per-wave LDS copies ----------------
__global__ __launch_bounds__(256) void hist1_k(const float* __restrict__ cube,
                                               unsigned* __restrict__ ws) {
    __shared__ unsigned h[4][2048];
    int tid = threadIdx.x, blk = blockIdx.x;
    int b = blk / 250, c = blk % 250;
    int wid = tid >> 6;
    for (int j = tid; j < 8192; j += 256) ((unsigned*)h)[j] = 0;
    __syncthreads();
    const float4* p = (const float4*)(cube + (size_t)b * Nn + (size_t)c * 16384);
    for (int it = 0; it < 16; ++it) {
        float4 v = p[it * 256 + tid];
        atomicAdd(&h[wid][fkey(v.x) >> 21], 1u);
        atomicAdd(&h[wid][fkey(v.y) >> 21], 1u);
        atomicAdd(&h[wid][fkey(v.z) >> 21], 1u);
        atomicAdd(&h[wid][fkey(v.w) >> 21], 1u);
    }
    __syncthreads();
    unsigned* g = ws + H1_OFF + b * 2048;
    for (int j = tid; j < 2048; j += 256) {
        unsigned s = h[0][j] + h[1][j] + h[2][j] + h[3][j];
        if (s) atomicAdd(&g[j], s);
    }
}

// ---------------- pick1 (also zeroes candidate counters) ----------------
__global__ __launch_bounds__(256) void pick1_k(unsigned* __restrict__ ws) {
    __shared__ unsigned sh[256];
    int tid = threadIdx.x, b = blockIdx.x;
    if (tid == 0) ws[CN_OFF + b] = 0;
    const unsigned* hist = ws + H1_OFF + b * 2048;
    unsigned loc[8], lsum = 0;
    for (int j = 0; j < 8; ++j) { loc[j] = hist[tid * 8 + j]; lsum += loc[j]; }
    sh[tid] = lsum; __syncthreads();
    for (int off = 1; off < 256; off <<= 1) {
        unsigned v = (tid >= off) ? sh[tid - off] : 0u; __syncthreads();
        sh[tid] += v; __syncthreads();
    }
    unsigned base = tid ? sh[tid - 1] : 0u;
    if (R0c >= base && R0c < base + lsum) {
        unsigned cacc = base;
        for (int j = 0; j < 8; ++j) {
            if (R0c < cacc + loc[j]) {
                ws[ST_OFF + b * 2] = (unsigned)(tid * 8 + j);
                ws[ST_OFF + b * 2 + 1] = R0c - cacc;
                break;
            }
            cacc += loc[j];
        }
    }
}

// ---------------- hist2: middle 11 bits gated on 11-bit prefix ----------------
__global__ __launch_bounds__(256) void hist2_k(const float* __restrict__ cube,
                                               unsigned* __restrict__ ws) {
    __shared__ unsigned h[2048];
    int tid = threadIdx.x, blk = blockIdx.x;
    int b = blk / 250, c = blk % 250;
    unsigned p11 = ws[ST_OFF + b * 2];
    for (int j = tid; j < 2048; j += 256) h[j] = 0;
    __syncthreads();
    const float4* p = (const float4*)(cube + (size_t)b * Nn + (size_t)c * 16384);
    for (int it = 0; it < 16; ++it) {
        float4 v = p[it * 256 + tid];
        float vv[4] = {v.x, v.y, v.z, v.w};
        for (int q = 0; q < 4; ++q) {
            unsigned k = fkey(vv[q]);
            if ((k >> 21) == p11) atomicAdd(&h[(k >> 10) & 0x7FFu], 1u);
        }
    }
    __syncthreads();
    unsigned* g = ws + H2_OFF + b * 2048;
    for (int j = tid; j < 2048; j += 256) if (h[j]) atomicAdd(&g[j], h[j]);
}

__global__ __launch_bounds__(256) void pick2_k(unsigned* __restrict__ ws) {
    __shared__ unsigned sh[256];
    int tid = threadIdx.x, b = blockIdx.x;
    const unsigned* hist = ws + H2_OFF + b * 2048;
    unsigned r = ws[ST_OFF + b * 2 + 1];
    unsigned pref = ws[ST_OFF + b * 2];
    unsigned loc[8], lsum = 0;
    for (int j = 0; j < 8; ++j) { loc[j] = hist[tid * 8 + j]; lsum += loc[j]; }
    sh[tid] = lsum; __syncthreads();
    for (int off = 1; off < 256; off <<= 1) {
        unsigned v = (tid >= off) ? sh[tid - off] : 0u; __syncthreads();
        sh[tid] += v; __syncthreads();
    }
    unsigned base = tid ? sh[tid - 1] : 0u;
    if (r >= base && r < base + lsum) {
        unsigned cacc = base;
        for (int j = 0; j < 8; ++j) {
            if (r < cacc + loc[j]) {
                ws[ST_OFF + b * 2] = (pref << 11) | (unsigned)(tid * 8 + j);
                ws[ST_OFF + b * 2 + 1] = r - cacc;
                break;
            }
            cacc += loc[j];
        }
    }
}

// ---------------- pass5: per-wave-chunk A-counts + candidate compact + hist3 ----------------
__global__ __launch_bounds__(256) void pass5_k(const float* __restrict__ cube,
                                               unsigned* __restrict__ ws) {
    int tid = threadIdx.x, blk = blockIdx.x;
    int lane = tid & 63, wid = tid >> 6;
    int b = blk / 250, c250 = blk % 250;
    const float* cb = cube + (size_t)b * Nn;
    unsigned p22 = ws[ST_OFF + b * 2];
    unsigned* H3g = ws + H3_OFF + b * 1024;
    for (int j = 0; j < 4; ++j) {
        int wc = c250 * 16 + wid * 4 + j;
        const float4* p = (const float4*)(cb + (size_t)wc * 1024);
        unsigned acnt = 0;
#define P5_ELEM(val) { unsigned k = fkey(val); acnt += ((k >> 10) > p22) ? 1u : 0u; \
    if ((k >> 10) == p22) { unsigned t = atomicAdd(&ws[CN_OFF + b], 1u); \
        if (t < CAP) ws[CAND_OFF + b * CAP + t] = ((unsigned)wc << 10) | (k & 1023u); \
        atomicAdd(&H3g[k & 1023u], 1u); } }
        for (int it = 0; it < 4; ++it) {
            float4 v = p[it * 64 + lane];
            P5_ELEM(v.x) P5_ELEM(v.y) P5_ELEM(v.z) P5_ELEM(v.w)
        }
#undef P5_ELEM
        for (int off = 32; off > 0; off >>= 1) acnt += __shfl_down(acnt, off, 64);
        if (lane == 0) ws[BC_OFF + b * NWC + wc] = acnt;
    }
}

// ---------------- finalize: pick3 + candidate fixup + 4000-entry scan ----------------
__global__ __launch_bounds__(256) void finalize_k(unsigned* __restrict__ ws) {
    __shared__ unsigned sh[256];
    __shared__ unsigned bcs[NWC];
    __shared__ unsigned keysh;
    int tid = threadIdx.x, b = blockIdx.x;

    // pick3: final low-10 walk -> full 32-bit key_lo
    {
        const unsigned* hist = ws + H3_OFF + b * 1024;
        unsigned r = ws[ST_OFF + b * 2 + 1];
        unsigned pref = ws[ST_OFF + b * 2];
        unsigned loc[4], lsum = 0;
        for (int j = 0; j < 4; ++j) { loc[j] = hist[tid * 4 + j]; lsum += loc[j]; }
        sh[tid] = lsum; __syncthreads();
        for (int off = 1; off < 256; off <<= 1) {
            unsigned v = (tid >= off) ? sh[tid - off] : 0u; __syncthreads();
            sh[tid] += v; __syncthreads();
        }
        unsigned base = tid ? sh[tid - 1] : 0u;
        if (r >= base && r < base + lsum) {
            unsigned cacc = base;
            for (int j = 0; j < 4; ++j) {
                if (r < cacc + loc[j]) {
                    unsigned key = (pref << 10) | (unsigned)(tid * 4 + j);
                    keysh = key;
                    ws[ST_OFF + b * 2] = key;   // scatter reads this
                    break;
                }
                cacc += loc[j];
            }
        }
    }
    __syncthreads();
    unsigned lo10 = keysh & 1023u;

    // load chunk counts, apply candidate fixup in LDS
    unsigned* bc = ws + BC_OFF + b * NWC;
    for (int j = tid; j < NWC; j += 256) bcs[j] = bc[j];
    unsigned n = ws[CN_OFF + b]; if (n > CAP) n = CAP;
    __syncthreads();
    for (unsigned t = tid; t < n; t += 256) {
        unsigned e = ws[CAND_OFF + b * CAP + t];
        if ((e & 1023u) > lo10) atomicAdd(&bcs[e >> 10], 1u);
    }
    __syncthreads();

    // exclusive scan of 4000 chunk counts
    unsigned loc[16], lsum = 0;
    for (int j = 0; j < 16; ++j) {
        int idx = tid * 16 + j;
        loc[j] = (idx < NWC) ? bcs[idx] : 0u;
        lsum += loc[j];
    }
    sh[tid] = lsum; __syncthreads();
    for (int off = 1; off < 256; off <<= 1) {
        unsigned v = (tid >= off) ? sh[tid - off] : 0u; __syncthreads();
        sh[tid] += v; __syncthreads();
    }
    unsigned run = tid ? sh[tid - 1] : 0u;
    for (int j = 0; j < 16; ++j) {
        int idx = tid * 16 + j;
        if (idx < NWC) bc[idx] = run;
        run += loc[j];
    }
    if (tid == 255) ws[CNT_OFF + b] = sh[255];
}

// ---------------- scatter: barrier-free ordered compaction + tail fill ----------------
__global__ __launch_bounds__(256) void scatter_k(const float* __restrict__ cube,
                                                 const float* __restrict__ dop,
                                                 float* __restrict__ out,
                                                 const unsigned* __restrict__ ws) {
    int tid = threadIdx.x, blk = blockIdx.x;
    int lane = tid & 63, wid = tid >> 6;
    int b = blk / 250, c250 = blk % 250;
    const float* cb = cube + (size_t)b * Nn;
    const float* db = dop + (size_t)b * Nn;
    unsigned keylo = ws[ST_OFF + b * 2];

    for (int j = 0; j < 4; ++j) {
        int wc = c250 * 16 + wid * 4 + j;
        unsigned run = ws[BC_OFF + b * NWC + wc];
        int base = wc * 1024;
#pragma unroll 4
        for (int it = 0; it < 16; ++it) {
            int i = base + it * 64 + lane;
            float x = cb[i];
            bool m = fkey(x) > keylo;
            unsigned long long bal = __ballot(m);
            if (m) {
                unsigned k = run + (unsigned)__popcll(bal & ((1ull << lane) - 1ull));
                size_t row = (size_t)b * Kn + k;
                int xi = i % 320;
                int t2 = i / 320;
                int yi = t2 % 320;
                int zi = t2 / 320;
                float* f = out + row * 5;
                f[0] = (float)xi / 320.0f * 72.0f;
                f[1] = (float)yi / 320.0f * 32.0f;
                f[2] = (float)zi / 40.0f * 8.0f;
                f[3] = x / 1e13f;
                f[4] = db[i] - 1.9326f;
                float4* s4 = (float4*)(out + OUT_SP + row * 4);  // 16B aligned
                *s4 = make_float4((float)b, (float)zi, (float)yi, (float)xi);
                out[OUT_VAL + row] = 1.0f;
            }
            run += (unsigned)__popcll(bal);
        }
    }
    // tail fill (outputs re-poisoned before every launch)
    for (int g = blk * 256 + tid; g < Bn * Kn; g += 1000 * 256) {
        int bb = g / Kn;
        int k = g - bb * Kn;
        if ((unsigned)k >= ws[CNT_OFF + bb]) {
            size_t row = (size_t)g;
            float* f = out + row * 5;
            f[0] = 0.f; f[1] = 0.f; f[2] = 0.f; f[3] = 0.f; f[4] = 0.f;
            float4* s4 = (float4*)(out + OUT_SP + row * 4);
            *s4 = make_float4(0.f, 0.f, 0.f, 0.f);
            out[OUT_VAL + row] = 0.f;
        }
    }
}

extern "C" void kernel_launch(void* const* d_in, const int* in_sizes, int n_in,
                              void* d_out, int out_size, void* d_ws, size_t ws_size,
                              hipStream_t stream) {
    const float* cube = (const float*)d_in[0];
    const float* dop = (const float*)d_in[1];
    float* out = (float*)d_out;
    unsigned* ws = (unsigned*)d_ws;

    // zero H1/H2/H3 histogram regions only
    hipMemsetAsync(d_ws, 0, (size_t)ST_OFF * sizeof(unsigned), stream);

    hipLaunchKernelGGL(hist1_k,    dim3(Bn * 250), dim3(256), 0, stream, cube, ws);
    hipLaunchKernelGGL(pick1_k,    dim3(Bn),       dim3(256), 0, stream, ws);
    hipLaunchKernelGGL(hist2_k,    dim3(Bn * 250), dim3(256), 0, stream, cube, ws);
    hipLaunchKernelGGL(pick2_k,    dim3(Bn),       dim3(256), 0, stream, ws);
    hipLaunchKernelGGL(pass5_k,    dim3(Bn * 250), dim3(256), 0, stream, cube, ws);
    hipLaunchKernelGGL(finalize_k, dim3(Bn),       dim3(256), 0, stream, ws);
    hipLaunchKernelGGL(scatter_k,  dim3(Bn * 250), dim3(256), 0, stream, cube, dop, out, ws);
}